// Round 5
// baseline (117.900 us; speedup 1.0000x reference)
//
#include <hip/hip_runtime.h>
#include <stdint.h>

// NVFP4 groupwise fake-quant, matching the XLA-SIMPLIFIED reference graph.
// XLA's algebraic simplifier rewrites div-by-constant to mul-by-RN(1/const):
//   x / fl32(1/6)        -> x * 6.0f          (RN_f32(1/fl32(1/6)) == 6.0 exactly)
//   amax / fl32(1/6) / 6 -> amax * RN(6*fl32(1/6)) = amax * 1.0 = amax  (exact)
// so the effective reference per group g, element i is:
//   sc  = round_e4m3_tiedown(amax)            [scale_pre == amax EXACTLY]
//   t   = RNE_f16( RN_f32( RN_f32(6*x) / sc ) )
//   out = RN_f32( RN_f32(sc * q) * fl32(1/6) )
// The one true divide has an e4m3 divisor (odd significand <= 15):
//   RN_f32(y/sc) == (float)((double)y * RN_double(1/sc))  provably
//   (quotient is >= 2^-30 relative from every f32 RNE boundary; exact
//   midpoints impossible since sc*midpoint needs >= 9*2^24 significand bits;
//   double-path error <= 2^-52). All f32 muls pinned with asm v_mul_f32,
//   f32->f16 RNE done in integer arithmetic -> immune to fast-math.

// RN_double(8/(8+k)) for e4m3 mantissa k = 0..7 (compile-time exact IEEE)
__constant__ double RECIP_M[8] = {
    8.0 / 8.0, 8.0 / 9.0, 8.0 / 10.0, 8.0 / 11.0,
    8.0 / 12.0, 8.0 / 13.0, 8.0 / 14.0, 8.0 / 15.0,
};

static __device__ __forceinline__ float mul_rn_asm(float a, float b) {
    float r;
    asm("v_mul_f32 %0, %1, %2" : "=v"(r) : "v"(a), "v"(b));
    return r;
}

// Integer f32->f16 RNE. |t| < 2^-14 -> 0 (far below the 0.25 FP4 cut, q=0
// either way). >= 65520 -> inf code (lands in the >=6.0 clamp either way).
static __device__ __forceinline__ unsigned f32_to_f16_rne_bits(float tf) {
    uint32_t fb = __float_as_uint(tf);
    uint32_t sign = (fb >> 16) & 0x8000u;
    uint32_t a = fb & 0x7FFFFFFFu;
    uint32_t h;
    if (a >= 0x477FF000u) {            // >= 65520.0 -> f16 inf
        h = 0x7C00u;
    } else if (a < 0x38800000u) {      // < 2^-14: q=0 region regardless
        h = 0u;
    } else {
        uint32_t m = a & 0x7FFFFFu;
        uint32_t base = (((a >> 23) - 112u) << 10) | (m >> 13);
        uint32_t r = m & 0x1FFFu;
        base += (uint32_t)((r > 0x1000u) || (r == 0x1000u && (base & 1u)));  // RNE
        h = base;                       // mantissa carry bumps exponent naturally
    }
    return h | sign;
}

// Integer f16->f32 (exact; q codes are 0 or normal f16)
static __device__ __forceinline__ float f16bits_to_f32(unsigned hb) {
    uint32_t s = (hb & 0x8000u) << 16;
    uint32_t em = hb & 0x7FFFu;
    uint32_t f = em ? ((((em >> 10) + 112u) << 23) | ((em & 0x3FFu) << 13)) : 0u;
    return __uint_as_float(f | s);
}

static __device__ __forceinline__ float quant_one(float x, float sc, double R_sc, float GMf) {
    float y = mul_rn_asm(x, 6.0f);          // RN_f32(6*x)   [XLA: x/GM -> x*6.0]
    float t = (float)((double)y * R_sc);    // == RN_f32(y / sc), proof above
    unsigned hb = f32_to_f16_rne_bits(t);
    unsigned sign = hb & 0x8000u;
    unsigned em   = hb & 0x7FFFu;
    // verbatim replication of _quant_fp4's uint16 ops (no wraparound occurs)
    unsigned m0 = (em >= 13312u) ? 1u : 0u;   // 0.25
    em *= m0;
    unsigned m1 = (em >= 14848u) ? 1u : 0u;   // 0.75
    em *= m1;
    unsigned b1 = (m0 - m1) * 14336u;         // -> 0.5
    unsigned m2 = (em >= 15360u) ? 1u : 0u;   // 1.0
    em *= m2;
    unsigned b2 = (m1 - m2) * 15360u;         // -> 1.0
    unsigned m3 = (em >= 17920u) ? 1u : 0u;   // 6.0
    em = em * (m2 - m3);
    unsigned b3 = m3 * 17920u;                // clamp -> 6.0
    unsigned uu = em & 32256u;                // exp + mantissa MSB
    unsigned rr = em & 256u;                  // next mantissa bit
    unsigned b4 = uu + 2u * rr;               // round-half-up on that bit
    float qf = f16bits_to_f32((b1 + b2 + b3 + b4 + sign) & 0xFFFFu);
    // out = (scale * q) * GM, fp32, exact association, pinned against refolding
    return mul_rn_asm(mul_rn_asm(sc, qf), GMf);
}

extern "C" __global__ __launch_bounds__(256)
void act_quant_kernel(const float* __restrict__ x, float* __restrict__ out, int n4) {
    const float GMf = __uint_as_float(0x3E2AAAABu);  // fl32(1/6), exact bits
    int stride = gridDim.x * blockDim.x;
    for (int i = blockIdx.x * blockDim.x + threadIdx.x; i < n4; i += stride) {
        const float4 v = reinterpret_cast<const float4*>(x)[i];
        // group amax: 4 elems per lane, group = aligned 4-lane quad (16 elems)
        float m = fmaxf(fmaxf(fabsf(v.x), fabsf(v.y)), fmaxf(fabsf(v.z), fabsf(v.w)));
        m = fmaxf(m, __shfl_xor(m, 1));
        m = fmaxf(m, __shfl_xor(m, 2));
        // scale_pre == amax exactly (XLA folds /GM/6 into *6*(1/6) -> *1.0)
        // round-to-e4m3-grid: keep 3 mantissa bits, ties toward smaller
        // magnitude (argmin-over-grid picks the lower index on midpoints)
        uint32_t sb = __float_as_uint(m);
        sb += 0x0007FFFFu;
        sb &= 0xFFF00000u;
        float sc = __uint_as_float(sb);
        sc = fminf(fmaxf(sc, 0.0078125f), 480.0f);  // grid range [2^-7, 480]
        // exact double reciprocal of e4m3 sc: table mantissa + exponent bits
        uint32_t cb = __float_as_uint(sc);
        int E = (int)((cb >> 23) & 0xFFu) - 127;
        double rm = RECIP_M[(cb >> 20) & 7u];
        unsigned long long rb = (unsigned long long)__double_as_longlong(rm)
                              - ((unsigned long long)(long long)E << 52);
        double R_sc = __longlong_as_double((long long)rb);

        float4 o;
        o.x = quant_one(v.x, sc, R_sc, GMf);
        o.y = quant_one(v.y, sc, R_sc, GMf);
        o.z = quant_one(v.z, sc, R_sc, GMf);
        o.w = quant_one(v.w, sc, R_sc, GMf);
        reinterpret_cast<float4*>(out)[i] = o;
    }
}

extern "C" void kernel_launch(void* const* d_in, const int* in_sizes, int n_in,
                              void* d_out, int out_size, void* d_ws, size_t ws_size,
                              hipStream_t stream) {
    const float* x = (const float*)d_in[0];
    float* out = (float*)d_out;
    int n4 = in_sizes[0] >> 2;           // total elements are a multiple of 16
    int block = 256;
    int grid = (n4 + block - 1) / block;
    if (grid > 2048) grid = 2048;        // grid-stride the rest
    act_quant_kernel<<<grid, block, 0, stream>>>(x, out, n4);
}

// Round 6
// 113.412 us; speedup vs baseline: 1.0396x; 1.0396x over previous
//
#include <hip/hip_runtime.h>
#include <stdint.h>

// NVFP4 groupwise fake-quant, bit-exact vs the XLA-simplified reference:
//   sc  = round_e4m3_tiedown(amax)                  [XLA folds /GM/6 -> *1.0]
//   t   = RNE_f16( RN_f32( RN_f32(6*x) / sc ) )     [XLA folds /GM -> *6.0]
//   out = RN_f32( RN_f32(sc * q(t)) * fl32(1/6) )
// (verified PASS absmax=0.0 in round 5)
//
// Round-6 speedup: the f16-cast + FP4 bucket emulation collapses to a step
// function of |t32|. All seven f16 bucket thresholds {0.25,0.75,1.25,1.75,
// 2.5,3.5,5.0} have EVEN f16 codes, so RNE ties round up and each cut is an
// inclusive >= against the f16 midpoint below the threshold — each exactly
// representable in f32:
//   0.25-2^-14, 0.75-2^-12, 1.25-2^-11, 1.75-2^-11, 2.5-2^-10, 3.5-2^-10,
//   5.0-2^-9.  q in {0,.5,1,1.5,2,3,4,6}; f16-inf (>=65520) and f16-subnormal
//   regions land in the correct end buckets automatically.
// The one true divide keeps the proven exact path: divisor is an e4m3 value
// (odd significand <= 15), so (float)((double)y * RN_double(1/sc)) ==
// RN_f32(y/sc) (quotient >= 2^-30 relative from every f32 RNE boundary;
// double-path error <= 2^-52; exact midpoints impossible). Compare-adds are
// exact in any FP mode (0.5-multiples, sums exact); pinned v_mul_f32 guards
// the remaining f32 muls from fast-math refolding.

// RN_double(8/(8+k)) for e4m3 mantissa k = 0..7 (compile-time exact IEEE)
__constant__ double RECIP_M[8] = {
    8.0 / 8.0, 8.0 / 9.0, 8.0 / 10.0, 8.0 / 11.0,
    8.0 / 12.0, 8.0 / 13.0, 8.0 / 14.0, 8.0 / 15.0,
};

static __device__ __forceinline__ float mul_rn_asm(float a, float b) {
    float r;
    asm("v_mul_f32 %0, %1, %2" : "=v"(r) : "v"(a), "v"(b));
    return r;
}

static __device__ __forceinline__ float quant_one(float x, float sc, double R_sc, float GMf) {
    float y = mul_rn_asm(x, 6.0f);          // RN_f32(6*x)
    float t = (float)((double)y * R_sc);    // == RN_f32(y / sc), proof above
    float a = fabsf(t);
    // q = FP4 bucket of RNE_f16(t): 7 branchless inclusive compares
    float q = 0.0f;
    q += (a >= 0.249938964843750f) ? 0.5f : 0.0f;   // 4095*2^-14
    q += (a >= 0.749755859375000f) ? 0.5f : 0.0f;   // 3071*2^-12
    q += (a >= 1.249511718750000f) ? 0.5f : 0.0f;   // 2559*2^-11
    q += (a >= 1.749511718750000f) ? 0.5f : 0.0f;   // 3583*2^-11
    q += (a >= 2.499023437500000f) ? 1.0f : 0.0f;   // 2559*2^-10
    q += (a >= 3.499023437500000f) ? 1.0f : 0.0f;   // 3583*2^-10
    q += (a >= 4.998046875000000f) ? 2.0f : 0.0f;   // 2559*2^-9
    float qs = copysignf(q, t);
    // out = (scale * q) * GM, fp32, exact association, pinned
    return mul_rn_asm(mul_rn_asm(sc, qs), GMf);
}

extern "C" __global__ __launch_bounds__(256)
void act_quant_kernel(const float* __restrict__ x, float* __restrict__ out, int n4) {
    const float GMf = __uint_as_float(0x3E2AAAABu);  // fl32(1/6), exact bits
    int stride = gridDim.x * blockDim.x;
    for (int i = blockIdx.x * blockDim.x + threadIdx.x; i < n4; i += stride) {
        const float4 v = reinterpret_cast<const float4*>(x)[i];
        // group amax: 4 elems per lane, group = aligned 4-lane quad (16 elems)
        float m = fmaxf(fmaxf(fabsf(v.x), fabsf(v.y)), fmaxf(fabsf(v.z), fabsf(v.w)));
        m = fmaxf(m, __shfl_xor(m, 1));
        m = fmaxf(m, __shfl_xor(m, 2));
        // scale_pre == amax exactly; round-to-e4m3-grid, ties toward smaller
        uint32_t sb = __float_as_uint(m);
        sb += 0x0007FFFFu;
        sb &= 0xFFF00000u;
        float sc = __uint_as_float(sb);
        sc = fminf(fmaxf(sc, 0.0078125f), 480.0f);  // e4m3 range [2^-7, 480]
        // exact double reciprocal of e4m3 sc: table mantissa + exponent bits
        uint32_t cb = __float_as_uint(sc);
        int E = (int)((cb >> 23) & 0xFFu) - 127;
        double rm = RECIP_M[(cb >> 20) & 7u];
        unsigned long long rb = (unsigned long long)__double_as_longlong(rm)
                              - ((unsigned long long)(long long)E << 52);
        double R_sc = __longlong_as_double((long long)rb);

        float4 o;
        o.x = quant_one(v.x, sc, R_sc, GMf);
        o.y = quant_one(v.y, sc, R_sc, GMf);
        o.z = quant_one(v.z, sc, R_sc, GMf);
        o.w = quant_one(v.w, sc, R_sc, GMf);
        reinterpret_cast<float4*>(out)[i] = o;
    }
}

extern "C" void kernel_launch(void* const* d_in, const int* in_sizes, int n_in,
                              void* d_out, int out_size, void* d_ws, size_t ws_size,
                              hipStream_t stream) {
    const float* x = (const float*)d_in[0];
    float* out = (float*)d_out;
    int n4 = in_sizes[0] >> 2;           // total elements are a multiple of 16
    int block = 256;
    int grid = (n4 + block - 1) / block;
    if (grid > 2048) grid = 2048;        // grid-stride the rest
    act_quant_kernel<<<grid, block, 0, stream>>>(x, out, n4);
}